// Round 17
// baseline (36.364 us; speedup 1.0000x reference)
//
#include <hip/hip_runtime.h>

// Exact Gaussian lattice filter: out = (W - I) @ U, W_ij = exp(-0.5*max(d2,0))
// N=8192, D=5 features, C=21 channels.
//
// R17: clean occupancy experiment. R12 numerics + ai C-operand fold (R16).
//  - JSPLIT=2: grid (256,2) = 512 blocks = 2 blocks/CU = 8 waves/SIMD
//    (R13 profile: 140 idle cyc/tile at 4 waves/SIMD, VALUBusy 60%).
//  - Epilogue identical per block: plain stores of the block's partial into
//    its own d_ws region (no atomics, no memset, no jc divergence — R15's
//    conflated costs removed).
//  - combine kernel: out = p0 + p1 - U, float4, 168 blocks (~1us).

#define NN 8192
#define CC 21
#define DD 5
#define NTILE_G (NN / 32)       // 256 j-tiles
#define ROWS 32                 // i-rows per block
#define NIB (NN / ROWS)         // 256
#define JSPLIT 2
#define TPB (NTILE_G / JSPLIT)  // 128 tiles per block-column
#define MAINT 1024              // 16 waves
#define NWAVE 16
#define TPW (TPB / NWAVE)       // 8 tiles per wave

#define F_OFF 0
#define U_OFF (NTILE_G * 64 * 16)          // 262144 B
#define P_OFF (U_OFF + NTILE_G * 2 * 64 * 16)   // 786432 B
#define PSZ   (NN * CC * 4)                // 688128 B per partial

typedef __attribute__((ext_vector_type(2)))  __fp16   fp16x2;
typedef __attribute__((ext_vector_type(8)))  _Float16 f16x8;
typedef __attribute__((ext_vector_type(16))) float    f32x16;
typedef __attribute__((ext_vector_type(4)))  unsigned u32x4;

// ---- pack kernel: F-frags (hi/lo + aj) then U-frags into ws (same as R12) ----
__global__ __launch_bounds__(256)
void pack_frags(const float* __restrict__ U, const float* __restrict__ ref,
                char* __restrict__ ws) {
    const float NH = -0.7213475204444817f;   // -0.5*log2(e)
    const int q = blockIdx.x * 256 + threadIdx.x;
    if (q < NTILE_G * 64) {
        const int tile = q >> 6, ln = q & 63;
        const int j = tile * 32 + (ln & 31);
        const float* fj = ref + (size_t)j * DD;
        _Float16 h_[5], l_[5];
        float sq = 0.f;
        #pragma unroll
        for (int d = 0; d < DD; ++d) {
            const float f = fj[d];
            sq = fmaf(f, f, sq);
            h_[d] = (_Float16)f;
            l_[d] = (_Float16)(f - (float)h_[d]);
        }
        const _Float16 aj = (_Float16)(NH * sq);
        _Float16 v[8] __attribute__((aligned(16)));
        if (ln < 32) {   // k0..7:  hj0..4, lj0, lj1, lj2
            v[0]=h_[0]; v[1]=h_[1]; v[2]=h_[2]; v[3]=h_[3];
            v[4]=h_[4]; v[5]=l_[0]; v[6]=l_[1]; v[7]=l_[2];
        } else {         // k8..15: lj3, lj4, hj0..4, aj
            v[0]=l_[3]; v[1]=l_[4]; v[2]=h_[0]; v[3]=h_[1];
            v[4]=h_[2]; v[5]=h_[3]; v[6]=h_[4]; v[7]=aj;
        }
        u32x4 pk; __builtin_memcpy(&pk, v, 16);
        *(u32x4*)(ws + F_OFF + (size_t)q * 16) = pk;
    } else {
        const int qu = q - NTILE_G * 64;
        const int ln = qu & 63, kt = (qu >> 6) & 1, tile = qu >> 7;
        const int c = ln & 31, g = ln >> 5;
        _Float16 v[8] __attribute__((aligned(16))) = {0,0,0,0,0,0,0,0};
        if (c < CC) {
            #pragma unroll
            for (int e = 0; e < 8; ++e) {
                const int j = tile * 32 + kt * 16 + (e & 3) + 8 * (e >> 2) + 4 * g;
                v[e] = (_Float16)U[(size_t)j * CC + c];
            }
        }
        u32x4 pk; __builtin_memcpy(&pk, v, 16);
        *(u32x4*)(ws + U_OFF + (size_t)qu * 16) = pk;
    }
}

// ---- main kernel ----
__global__ __launch_bounds__(MAINT, 8)
void lattice_main(const float* __restrict__ U, const float* __restrict__ ref,
                  char* __restrict__ ws, float* __restrict__ out) {
    __shared__ __align__(16) float red[NWAVE * ROWS * 32];   // 64 KB

    const int t    = threadIdx.x;
    const int lane = t & 63;
    const int wv   = t >> 6;        // wave 0..15
    const int h    = lane >> 5;
    const int m    = lane & 31;
    const int ibase = blockIdx.x * ROWS;
    const int jc    = blockIdx.y;   // 0..1
    const float L  = 1.4426950408889634f;    // log2(e)
    const float NH = -0.7213475204444817f;   // -0.5*log2(e)

    // ---- per-lane i-row: ai (fp32) and L-scaled hi/lo f16 B-fragment ----
    const float* fiP = ref + (size_t)(ibase + m) * DD;
    const float fi0 = fiP[0], fi1 = fiP[1], fi2 = fiP[2], fi3 = fiP[3], fi4 = fiP[4];
    const float ai = NH * (fi0*fi0 + fi1*fi1 + fi2*fi2 + fi3*fi3 + fi4*fi4);
    f16x8 bfi;
    {
        const float sf[5] = {L*fi0, L*fi1, L*fi2, L*fi3, L*fi4};
        _Float16 hi_[5], lo_[5];
        #pragma unroll
        for (int d = 0; d < DD; ++d) {
            hi_[d] = (_Float16)sf[d];
            lo_[d] = (_Float16)(sf[d] - (float)hi_[d]);
        }
        // B_i k-slots: k0..7 (h=0): {Lhi0..4, Lhi0, Lhi1, Lhi2}
        //              k8..15 (h=1): {Lhi3, Lhi4, Llo0..4, 1.0}
        _Float16 bv[8] __attribute__((aligned(16)));
        bv[0] = h ? hi_[3] : hi_[0];
        bv[1] = h ? hi_[4] : hi_[1];
        bv[2] = h ? lo_[0] : hi_[2];
        bv[3] = h ? lo_[1] : hi_[3];
        bv[4] = h ? lo_[2] : hi_[4];
        bv[5] = h ? lo_[3] : hi_[0];
        bv[6] = h ? lo_[4] : hi_[1];
        bv[7] = h ? (_Float16)1.0f : hi_[2];
        __builtin_memcpy(&bfi, bv, 16);
    }

    // loop-invariant C-init: adds ai inside the S-MFMA (col-constant)
    f32x16 cini;
    #pragma unroll
    for (int r = 0; r < 16; ++r) cini[r] = ai;

    f32x16 acc;
    #pragma unroll
    for (int r = 0; r < 16; ++r) acc[r] = 0.f;

    const char* Fws = ws + F_OFF;
    const char* Uws = ws + U_OFF;
    const int tile0 = jc * TPB + wv * TPW;

    // ---- main loop: 8 tiles, single stream ----
    for (int s = 0; s < TPW; ++s) {
        const int tile = tile0 + s;
        const u32x4 fr = *(const u32x4*)(Fws + ((size_t)(tile * 64 + lane)) * 16);
        const u32x4 b0 = *(const u32x4*)(Uws + ((size_t)((tile * 2 + 0) * 64 + lane)) * 16);
        const u32x4 b1 = *(const u32x4*)(Uws + ((size_t)((tile * 2 + 1) * 64 + lane)) * 16);

        f32x16 sacc = __builtin_amdgcn_mfma_f32_32x32x16_f16(
            __builtin_bit_cast(f16x8, fr), bfi, cini, 0, 0, 0);
        // sacc[r] = ai + aj + L*(fi.fj)  for j_local=(r&3)+8*(r>>2)+4h, i=m

        float e[16];
        #pragma unroll
        for (int r = 0; r < 16; ++r)
            e[r] = __builtin_amdgcn_exp2f(sacc[r]);

        fp16x2 p[8];
        #pragma unroll
        for (int k = 0; k < 8; ++k)
            p[k] = __builtin_amdgcn_cvt_pkrtz(e[2*k], e[2*k+1]);
        f16x8 a0, a1;
        __builtin_memcpy(&a0, &p[0], 16);
        __builtin_memcpy(&a1, &p[4], 16);

        acc = __builtin_amdgcn_mfma_f32_32x32x16_f16(
            a0, __builtin_bit_cast(f16x8, b0), acc, 0, 0, 0);
        acc = __builtin_amdgcn_mfma_f32_32x32x16_f16(
            a1, __builtin_bit_cast(f16x8, b1), acc, 0, 0, 0);
    }

    // ---- write partials: red[wv][row][m] ----
    #pragma unroll
    for (int r = 0; r < 16; ++r) {
        const int row = (r & 3) + 8 * (r >> 2) + 4 * h;
        red[wv * (ROWS * 32) + row * 32 + m] = acc[r];
    }
    __syncthreads();

    // ---- reduce 16 waves -> plain store into this jc's partial buffer ----
    {
        float* po = (float*)(ws + P_OFF + (size_t)jc * PSZ);
        const int row = t >> 5, col = t & 31;
        float s = 0.f;
        #pragma unroll
        for (int w = 0; w < NWAVE; ++w) s += red[w * (ROWS * 32) + row * 32 + col];
        if (col < CC)
            po[(size_t)(ibase + row) * CC + col] = s;
    }
}

// ---- combine: out = p0 + p1 - U (float4; 43008 quads) ----
__global__ __launch_bounds__(256)
void combine(const char* __restrict__ ws, const float* __restrict__ U,
             float* __restrict__ out) {
    const int i = blockIdx.x * 256 + threadIdx.x;
    const float4* p0 = (const float4*)(ws + P_OFF);
    const float4* p1 = (const float4*)(ws + P_OFF + PSZ);
    const float4 a = p0[i];
    const float4 b = p1[i];
    const float4 u = ((const float4*)U)[i];
    float4 o;
    o.x = a.x + b.x - u.x;
    o.y = a.y + b.y - u.y;
    o.z = a.z + b.z - u.z;
    o.w = a.w + b.w - u.w;
    ((float4*)out)[i] = o;
}

extern "C" void kernel_launch(void* const* d_in, const int* in_sizes, int n_in,
                              void* d_out, int out_size, void* d_ws, size_t ws_size,
                              hipStream_t stream) {
    const float* U   = (const float*)d_in[0];
    const float* ref = (const float*)d_in[1];
    float* out = (float*)d_out;
    char* ws = (char*)d_ws;   // needs ~2.1 MB

    const int pack_threads = NTILE_G * 64 + NTILE_G * 2 * 64;   // 49152
    pack_frags<<<pack_threads / 256, 256, 0, stream>>>(U, ref, ws);

    dim3 grid(NIB, JSPLIT);
    lattice_main<<<grid, MAINT, 0, stream>>>(U, ref, ws, out);

    combine<<<(NN * CC / 4) / 256, 256, 0, stream>>>(ws, U, out);
}

// Round 18
// 22.387 us; speedup vs baseline: 1.6243x; 1.6243x over previous
//
#include <hip/hip_runtime.h>

// Exact Gaussian lattice filter: out = (W - I) @ U, W_ij = exp(-0.5*max(d2,0))
// N=8192, D=5 features, C=21 channels.
//
// R18 = verbatim revert to R12, the measured optimum (22.4 us).
// Structure: f16 MFMA hybrid, 2 graph nodes.
//  - pack kernel: F-frags (hi/lo split + aj in k15) + U-frags -> d_ws (768 KB)
//  - main: 256 blocks x 1024 thr (16 waves); each block owns 32 i-rows, each
//    wave 16 j-tiles. Per tile: 3 global b128 frag loads, S-MFMA
//    (S = L*(fi.fj) + aj via hi/lo f16 split; only ~2^-22 terms dropped),
//    x = ai + S in fp32, w = exp2(x), f16 pack, 2 U-MFMAs (fp32 accum).
//  - epilogue: 16-wave LDS reduce -> plain stores out = sum - U
//    (no atomics, no memset; poison-proof).
// Rounds 14-17 (occupancy 2x, 2-stream ILP, split epilogues) all regressed;
// R10 prefetch neutral. Main loop runs at ~72% of the chip VALU/trans issue
// floor (R13 counters: VALUBusy-modeled == measured within 3%).

#define NN 8192
#define CC 21
#define DD 5
#define NTILE_G (NN / 32)       // 256 j-tiles
#define ROWS 32                 // i-rows per block
#define NIB (NN / ROWS)         // 256 blocks
#define MAINT 1024              // 16 waves
#define NWAVE 16
#define TPW (NTILE_G / NWAVE)   // 16 tiles per wave

#define F_OFF 0
#define U_OFF (NTILE_G * 64 * 16)   // 262144 B

typedef __attribute__((ext_vector_type(8)))  _Float16 f16x8;
typedef __attribute__((ext_vector_type(16))) float    f32x16;
typedef __attribute__((ext_vector_type(4)))  unsigned u32x4;

// ---- pack kernel: F-frags (hi/lo + aj) then U-frags into ws ----
__global__ __launch_bounds__(256)
void pack_frags(const float* __restrict__ U, const float* __restrict__ ref,
                char* __restrict__ ws) {
    const float NH = -0.7213475204444817f;   // -0.5*log2(e)
    const int q = blockIdx.x * 256 + threadIdx.x;
    if (q < NTILE_G * 64) {
        // F-frag slot: tile = q>>6, frag-lane ln = q&63, j = tile*32 + (ln&31)
        const int tile = q >> 6, ln = q & 63;
        const int j = tile * 32 + (ln & 31);
        const float* fj = ref + (size_t)j * DD;
        _Float16 h_[5], l_[5];
        float sq = 0.f;
        #pragma unroll
        for (int d = 0; d < DD; ++d) {
            const float f = fj[d];
            sq = fmaf(f, f, sq);
            h_[d] = (_Float16)f;
            l_[d] = (_Float16)(f - (float)h_[d]);
        }
        const _Float16 aj = (_Float16)(NH * sq);
        _Float16 v[8] __attribute__((aligned(16)));
        if (ln < 32) {   // k0..7:  hj0..4, lj0, lj1, lj2
            v[0]=h_[0]; v[1]=h_[1]; v[2]=h_[2]; v[3]=h_[3];
            v[4]=h_[4]; v[5]=l_[0]; v[6]=l_[1]; v[7]=l_[2];
        } else {         // k8..15: lj3, lj4, hj0..4, aj
            v[0]=l_[3]; v[1]=l_[4]; v[2]=h_[0]; v[3]=h_[1];
            v[4]=h_[2]; v[5]=h_[3]; v[6]=h_[4]; v[7]=aj;
        }
        u32x4 pk; __builtin_memcpy(&pk, v, 16);
        *(u32x4*)(ws + F_OFF + (size_t)q * 16) = pk;
    } else {
        // U-frag slot: qu = q - 16384: tile=qu>>7, kt=(qu>>6)&1, ln=qu&63
        const int qu = q - NTILE_G * 64;
        const int ln = qu & 63, kt = (qu >> 6) & 1, tile = qu >> 7;
        const int c = ln & 31, g = ln >> 5;
        _Float16 v[8] __attribute__((aligned(16))) = {0,0,0,0,0,0,0,0};
        if (c < CC) {
            #pragma unroll
            for (int e = 0; e < 8; ++e) {
                const int j = tile * 32 + kt * 16 + (e & 3) + 8 * (e >> 2) + 4 * g;
                v[e] = (_Float16)U[(size_t)j * CC + c];
            }
        }
        u32x4 pk; __builtin_memcpy(&pk, v, 16);
        *(u32x4*)(ws + U_OFF + (size_t)qu * 16) = pk;
    }
}

// ---- main kernel ----
__global__ __launch_bounds__(MAINT, 4)
void lattice_main(const float* __restrict__ U, const float* __restrict__ ref,
                  const char* __restrict__ ws, float* __restrict__ out) {
    __shared__ __align__(16) float red[NWAVE * ROWS * 32];   // 64 KB

    const int t    = threadIdx.x;
    const int lane = t & 63;
    const int wv   = t >> 6;        // wave 0..15
    const int h    = lane >> 5;
    const int m    = lane & 31;
    const int ibase = blockIdx.x * ROWS;
    const float L  = 1.4426950408889634f;    // log2(e)
    const float NH = -0.7213475204444817f;   // -0.5*log2(e)

    // ---- per-lane i-row: ai (fp32) and L-scaled hi/lo f16 B-fragment ----
    const float* fiP = ref + (size_t)(ibase + m) * DD;
    const float fi0 = fiP[0], fi1 = fiP[1], fi2 = fiP[2], fi3 = fiP[3], fi4 = fiP[4];
    const float ai = NH * (fi0*fi0 + fi1*fi1 + fi2*fi2 + fi3*fi3 + fi4*fi4);
    f16x8 bfi;
    {
        const float sf[5] = {L*fi0, L*fi1, L*fi2, L*fi3, L*fi4};
        _Float16 hi_[5], lo_[5];
        #pragma unroll
        for (int d = 0; d < DD; ++d) {
            hi_[d] = (_Float16)sf[d];
            lo_[d] = (_Float16)(sf[d] - (float)hi_[d]);
        }
        // B_i k-slots: k0..7 (h=0): {Lhi0..4, Lhi0, Lhi1, Lhi2}
        //              k8..15 (h=1): {Lhi3, Lhi4, Llo0..4, 1.0}
        _Float16 bv[8] __attribute__((aligned(16)));
        bv[0] = h ? hi_[3] : hi_[0];
        bv[1] = h ? hi_[4] : hi_[1];
        bv[2] = h ? lo_[0] : hi_[2];
        bv[3] = h ? lo_[1] : hi_[3];
        bv[4] = h ? lo_[2] : hi_[4];
        bv[5] = h ? lo_[3] : hi_[0];
        bv[6] = h ? lo_[4] : hi_[1];
        bv[7] = h ? (_Float16)1.0f : hi_[2];
        __builtin_memcpy(&bfi, bv, 16);
    }

    f32x16 acc;
    #pragma unroll
    for (int r = 0; r < 16; ++r) acc[r] = 0.f;

    const char* Fws = ws + F_OFF;
    const char* Uws = ws + U_OFF;
    const int tile0 = wv * TPW;

    // ---- main loop: 16 tiles, no barriers, no LDS ----
    for (int s = 0; s < TPW; ++s) {
        const int tile = tile0 + s;
        const u32x4 fr = *(const u32x4*)(Fws + ((size_t)(tile * 64 + lane)) * 16);
        const u32x4 b0 = *(const u32x4*)(Uws + ((size_t)((tile * 2 + 0) * 64 + lane)) * 16);
        const u32x4 b1 = *(const u32x4*)(Uws + ((size_t)((tile * 2 + 1) * 64 + lane)) * 16);

        f32x16 sacc;
        #pragma unroll
        for (int r = 0; r < 16; ++r) sacc[r] = 0.f;
        sacc = __builtin_amdgcn_mfma_f32_32x32x16_f16(
            __builtin_bit_cast(f16x8, fr), bfi, sacc, 0, 0, 0);
        // sacc[r] = L*(fi.fj) + aj  for j_local = (r&3)+8*(r>>2)+4h, i = m

        _Float16 wv16[16] __attribute__((aligned(16)));
        #pragma unroll
        for (int r = 0; r < 16; ++r)
            wv16[r] = (_Float16)__builtin_amdgcn_exp2f(ai + sacc[r]);
        f16x8 a0, a1;
        __builtin_memcpy(&a0, &wv16[0], 16);
        __builtin_memcpy(&a1, &wv16[8], 16);

        acc = __builtin_amdgcn_mfma_f32_32x32x16_f16(
            a0, __builtin_bit_cast(f16x8, b0), acc, 0, 0, 0);
        acc = __builtin_amdgcn_mfma_f32_32x32x16_f16(
            a1, __builtin_bit_cast(f16x8, b1), acc, 0, 0, 0);
    }

    // ---- write partials: red[wv][row][m] ----
    #pragma unroll
    for (int r = 0; r < 16; ++r) {
        const int row = (r & 3) + 8 * (r >> 2) + 4 * h;
        red[wv * (ROWS * 32) + row * 32 + m] = acc[r];
    }
    __syncthreads();

    // ---- reduce 16 waves -> out = sum - U (plain stores) ----
    {
        const int row = t >> 5, col = t & 31;
        float s = 0.f;
        #pragma unroll
        for (int w = 0; w < NWAVE; ++w) s += red[w * (ROWS * 32) + row * 32 + col];
        if (col < CC) {
            const size_t o = (size_t)(ibase + row) * CC + col;
            out[o] = s - U[o];
        }
    }
}

extern "C" void kernel_launch(void* const* d_in, const int* in_sizes, int n_in,
                              void* d_out, int out_size, void* d_ws, size_t ws_size,
                              hipStream_t stream) {
    const float* U   = (const float*)d_in[0];
    const float* ref = (const float*)d_in[1];
    float* out = (float*)d_out;
    char* ws = (char*)d_ws;   // needs 768 KB

    const int pack_threads = NTILE_G * 64 + NTILE_G * 2 * 64;   // 49152
    pack_frags<<<pack_threads / 256, 256, 0, stream>>>(U, ref, ws);
    lattice_main<<<NIB, MAINT, 0, stream>>>(U, ref, (const char*)ws, out);
}